// Round 2
// baseline (226.377 us; speedup 1.0000x reference)
//
#include <hip/hip_runtime.h>

#define N_TOK  8192
#define KDIM   4096
#define NE     16
#define NSLICE 8                   // K split across blocks -> 1024 blocks = 4/CU
#define TB     64                  // tokens per block (= wave width)
#define BK     32                  // k per staged chunk per wave
#define NWAVE  4                   // waves per block (256 threads)
#define KSLICE (KDIM / NSLICE)     // 512
#define KWAVE  (KSLICE / NWAVE)    // 128
#define NCHUNK (KWAVE / BK)        // 4
#define LSTR   36                  // 9 float4: odd-in-float4 -> b128 conflict-free, 16B aligned

// Kernel A: partial logits. Lane <-> token, k wave-uniform so gate reads are
// scalar (s_load) and the inner loop is v_fmac(v_acc, s_gate, v_x).
// Per-wave private LDS tile -> NO __syncthreads in the K loop.
// LDS via b128 only: stride 36 floats => lane t's float4 row lands in bank
// group 4*((t+j)%8); 8 lanes per group x 8 phases = 256-word minimum (free).
__global__ __launch_bounds__(256, 4)
void router_partial(const float* __restrict__ x, const float* __restrict__ gate,
                    float* __restrict__ ws) {
  __shared__ float lds[NWAVE * TB * LSTR];   // 4*64*36*4B = 36.9 KB -> 4 blocks/CU
  const int tid  = threadIdx.x;
  const int lane = tid & 63;
  const int w    = __builtin_amdgcn_readfirstlane(tid >> 6);  // SGPR: keeps gate addr uniform
  const int g    = blockIdx.x >> 3;          // token group (128 groups)
  const int s    = blockIdx.x & 7;           // k-slice
  const int t0   = g * TB;
  const int k0   = s * KSLICE + w * KWAVE;
  float* xt = lds + w * (TB * LSTR);

  float acc[NE];
#pragma unroll
  for (int e = 0; e < NE; ++e) acc[e] = 0.f;

  // stage chunk 0: 64 tok x 32 k = 512 float4, 8 per lane, 128B-contiguous/8 lanes
  float4 buf[8];
#pragma unroll
  for (int i = 0; i < 8; ++i) {
    int f = i * 64 + lane;
    int t = f >> 3, c4 = f & 7;              // 8 float4 per token row
    buf[i] = *(const float4*)(x + (size_t)(t0 + t) * KDIM + (k0 + c4 * 4));
  }

  for (int c = 0; c < NCHUNK; ++c) {
    // write staged chunk to LDS as b128 (16B aligned: t*36 + c4*4 words)
#pragma unroll
    for (int i = 0; i < 8; ++i) {
      int f = i * 64 + lane;
      int t = f >> 3, c4 = f & 7;
      *(float4*)(xt + t * LSTR + c4 * 4) = buf[i];
    }
    // prefetch next chunk before compute: global latency hidden by 512 FMAs
    if (c + 1 < NCHUNK) {
      int kc = k0 + (c + 1) * BK;
#pragma unroll
      for (int i = 0; i < 8; ++i) {
        int f = i * 64 + lane;
        int t = f >> 3, c4 = f & 7;
        buf[i] = *(const float4*)(x + (size_t)(t0 + t) * KDIM + (kc + c4 * 4));
      }
    }
    int kc = k0 + c * BK;
    const float4* xrow4 = (const float4*)(xt + lane * LSTR);  // 144B offset, 16B aligned
#pragma unroll
    for (int j = 0; j < 8; ++j) {            // 8 ds_read_b128, 64 FMA each
      float4 xv4 = xrow4[j];
      const float xv[4] = {xv4.x, xv4.y, xv4.z, xv4.w};
#pragma unroll
      for (int m = 0; m < 4; ++m) {
        const float* grow = gate + (size_t)(kc + j * 4 + m) * NE;  // wave-uniform -> s_load
#pragma unroll
        for (int e = 0; e < NE; ++e) acc[e] = fmaf(xv[m], grow[e], acc[e]);
      }
    }
  }

  // cross-wave reduction of the 4 k-subslices, then one ws write per block
  __syncthreads();                           // waves done reading xt before overwrite
  float* red = lds;                          // reuse as [256][17]
#pragma unroll
  for (int e = 0; e < NE; ++e) red[(w * 64 + lane) * 17 + e] = acc[e];
  __syncthreads();
  {
    int p0 = tid * 4;                        // 1024 (token,e) pairs, 4 per thread
    int t  = p0 >> 4, e0 = p0 & 15;
    float v[4];
#pragma unroll
    for (int j = 0; j < 4; ++j) {
      float sum = 0.f;
#pragma unroll
      for (int ww = 0; ww < NWAVE; ++ww) sum += red[(ww * 64 + t) * 17 + e0 + j];
      v[j] = sum;
    }
    *(float4*)(ws + ((size_t)s * N_TOK + (t0 + t)) * NE + e0) =
        make_float4(v[0], v[1], v[2], v[3]);
  }
}

// Kernel B: sum 8 slice partials, top-2 (earliest-index tie-break = jax top_k),
// sigmoid, scatter into (E,N) scores; token_indices[e][t] = t (as float).
__global__ __launch_bounds__(256)
void router_finalize(const float* __restrict__ ws, float* __restrict__ out) {
  int t = blockIdx.x * 256 + threadIdx.x;
  float l[NE];
#pragma unroll
  for (int e = 0; e < NE; ++e) l[e] = 0.f;
#pragma unroll
  for (int s = 0; s < NSLICE; ++s) {
    const float* row = ws + ((size_t)s * N_TOK + t) * NE;  // 64B contiguous/thread
#pragma unroll
    for (int e = 0; e < NE; ++e) l[e] += row[e];
  }
  int i1 = 0; float v1 = l[0];
#pragma unroll
  for (int e = 1; e < NE; ++e) { if (l[e] > v1) { v1 = l[e]; i1 = e; } }
  int i2 = -1; float v2 = -1e30f;
#pragma unroll
  for (int e = 0; e < NE; ++e) { if (e != i1 && l[e] > v2) { v2 = l[e]; i2 = e; } }
  float s1 = 1.f / (1.f + __expf(-v1));
  float s2 = 1.f / (1.f + __expf(-v2));
  float* scores = out;
  float* tix    = out + (size_t)NE * N_TOK;
  float tf = (float)t;
#pragma unroll
  for (int e = 0; e < NE; ++e) {             // coalesced across lanes per e
    scores[(size_t)e * N_TOK + t] = (e == i1) ? s1 : ((e == i2) ? s2 : 0.f);
    tix[(size_t)e * N_TOK + t]    = tf;
  }
}

extern "C" void kernel_launch(void* const* d_in, const int* in_sizes, int n_in,
                              void* d_out, int out_size, void* d_ws, size_t ws_size,
                              hipStream_t stream) {
  const float* x    = (const float*)d_in[0];
  const float* gate = (const float*)d_in[1];
  float* out = (float*)d_out;
  float* ws  = (float*)d_ws;   // needs NSLICE*N_TOK*NE*4 = 4 MB
  router_partial<<<dim3(N_TOK / TB * NSLICE), dim3(256), 0, stream>>>(x, gate, ws);
  router_finalize<<<dim3(N_TOK / 256), dim3(256), 0, stream>>>(ws, out);
}

// Round 3
// 226.151 us; speedup vs baseline: 1.0010x; 1.0010x over previous
//
#include <hip/hip_runtime.h>

#define N_TOK  8192
#define KDIM   4096
#define NE     16
#define NSLICE 8                   // K split across blocks -> 1024 blocks = 4/CU
#define TB     64                  // tokens per block (= wave width)
#define BK     32                  // k per staged chunk per wave
#define NWAVE  4                   // waves per block (256 threads)
#define KSLICE (KDIM / NSLICE)     // 512
#define KWAVE  (KSLICE / NWAVE)    // 128
#define NCHUNK (KWAVE / BK)        // 4
#define LSTR   36                  // 9 float4: odd-in-float4 -> b128 conflict-free, 16B aligned

// Kernel A: partial logits. Lane <-> token, k wave-uniform so gate reads are
// scalar (s_load) and the inner loop is v_fmac(v_acc, s_gate, v_x).
// Per-wave private LDS tile -> NO __syncthreads in the K loop.
// launch_bounds(256,2): round-2's (256,4) made the compiler spill the buf[8]
// prefetch to scratch (WRITE_SIZE 128 MB, VGPR=52) -> 89us. Cap occupancy
// pressure, keep buf in VGPRs.
__global__ __launch_bounds__(256, 2)
void router_partial(const float* __restrict__ x, const float* __restrict__ gate,
                    float* __restrict__ ws) {
  __shared__ float lds[NWAVE * TB * LSTR];   // 4*64*36*4B = 36.9 KB
  const int tid  = threadIdx.x;
  const int lane = tid & 63;
  const int w    = __builtin_amdgcn_readfirstlane(tid >> 6);  // SGPR: keeps gate addr uniform
  const int g    = blockIdx.x >> 3;          // token group (128 groups)
  const int s    = blockIdx.x & 7;           // k-slice
  const int t0   = g * TB;
  const int k0   = s * KSLICE + w * KWAVE;
  float* xt = lds + w * (TB * LSTR);

  float acc[NE];
#pragma unroll
  for (int e = 0; e < NE; ++e) acc[e] = 0.f;

  // stage chunk 0: 64 tok x 32 k = 512 float4, 8 per lane, 128B-contiguous/8 lanes
  float4 buf[8];
#pragma unroll
  for (int i = 0; i < 8; ++i) {
    int f = i * 64 + lane;
    int t = f >> 3, c4 = f & 7;              // 8 float4 per token row
    buf[i] = *(const float4*)(x + (size_t)(t0 + t) * KDIM + (k0 + c4 * 4));
  }

  for (int c = 0; c < NCHUNK; ++c) {
    // write staged chunk to LDS as b128 (16B aligned: t*36 + c4*4 words)
#pragma unroll
    for (int i = 0; i < 8; ++i) {
      int f = i * 64 + lane;
      int t = f >> 3, c4 = f & 7;
      *(float4*)(xt + t * LSTR + c4 * 4) = buf[i];
    }
    // prefetch next chunk before compute: global latency hidden by 512 FMAs
    if (c + 1 < NCHUNK) {
      int kc = k0 + (c + 1) * BK;
#pragma unroll
      for (int i = 0; i < 8; ++i) {
        int f = i * 64 + lane;
        int t = f >> 3, c4 = f & 7;
        buf[i] = *(const float4*)(x + (size_t)(t0 + t) * KDIM + (kc + c4 * 4));
      }
    }
    int kc = k0 + c * BK;
    const float4* xrow4 = (const float4*)(xt + lane * LSTR);  // 144B offset, 16B aligned
#pragma unroll
    for (int j = 0; j < 8; ++j) {            // 8 ds_read_b128, 64 FMA each
      float4 xv4 = xrow4[j];
      const float xv[4] = {xv4.x, xv4.y, xv4.z, xv4.w};
#pragma unroll
      for (int m = 0; m < 4; ++m) {
        const float* grow = gate + (size_t)(kc + j * 4 + m) * NE;  // wave-uniform -> s_load
#pragma unroll
        for (int e = 0; e < NE; ++e) acc[e] = fmaf(xv[m], grow[e], acc[e]);
      }
    }
  }

  // cross-wave reduction of the 4 k-subslices, then one ws write per block
  __syncthreads();                           // waves done reading xt before overwrite
  float* red = lds;                          // reuse as [256][17]
#pragma unroll
  for (int e = 0; e < NE; ++e) red[(w * 64 + lane) * 17 + e] = acc[e];
  __syncthreads();
  {
    int p0 = tid * 4;                        // 1024 (token,e) pairs, 4 per thread
    int t  = p0 >> 4, e0 = p0 & 15;
    float v[4];
#pragma unroll
    for (int j = 0; j < 4; ++j) {
      float sum = 0.f;
#pragma unroll
      for (int ww = 0; ww < NWAVE; ++ww) sum += red[(ww * 64 + t) * 17 + e0 + j];
      v[j] = sum;
    }
    *(float4*)(ws + ((size_t)s * N_TOK + (t0 + t)) * NE + e0) =
        make_float4(v[0], v[1], v[2], v[3]);
  }
}

// Kernel B: sum 8 slice partials, top-2 (earliest-index tie-break = jax top_k),
// sigmoid, scatter into (E,N) scores; token_indices[e][t] = t (as float).
__global__ __launch_bounds__(256)
void router_finalize(const float* __restrict__ ws, float* __restrict__ out) {
  int t = blockIdx.x * 256 + threadIdx.x;
  float l[NE];
#pragma unroll
  for (int e = 0; e < NE; ++e) l[e] = 0.f;
#pragma unroll
  for (int s = 0; s < NSLICE; ++s) {
    const float* row = ws + ((size_t)s * N_TOK + t) * NE;  // 64B contiguous/thread
#pragma unroll
    for (int e = 0; e < NE; ++e) l[e] += row[e];
  }
  int i1 = 0; float v1 = l[0];
#pragma unroll
  for (int e = 1; e < NE; ++e) { if (l[e] > v1) { v1 = l[e]; i1 = e; } }
  int i2 = -1; float v2 = -1e30f;
#pragma unroll
  for (int e = 0; e < NE; ++e) { if (e != i1 && l[e] > v2) { v2 = l[e]; i2 = e; } }
  float s1 = 1.f / (1.f + __expf(-v1));
  float s2 = 1.f / (1.f + __expf(-v2));
  float* scores = out;
  float* tix    = out + (size_t)NE * N_TOK;
  float tf = (float)t;
#pragma unroll
  for (int e = 0; e < NE; ++e) {             // coalesced across lanes per e
    scores[(size_t)e * N_TOK + t] = (e == i1) ? s1 : ((e == i2) ? s2 : 0.f);
    tix[(size_t)e * N_TOK + t]    = tf;
  }
}

extern "C" void kernel_launch(void* const* d_in, const int* in_sizes, int n_in,
                              void* d_out, int out_size, void* d_ws, size_t ws_size,
                              hipStream_t stream) {
  const float* x    = (const float*)d_in[0];
  const float* gate = (const float*)d_in[1];
  float* out = (float*)d_out;
  float* ws  = (float*)d_ws;   // needs NSLICE*N_TOK*NE*4 = 4 MB
  router_partial<<<dim3(N_TOK / TB * NSLICE), dim3(256), 0, stream>>>(x, gate, ws);
  router_finalize<<<dim3(N_TOK / 256), dim3(256), 0, stream>>>(ws, out);
}

// Round 4
// 205.305 us; speedup vs baseline: 1.1026x; 1.1015x over previous
//
#include <hip/hip_runtime.h>

#define N_TOK  8192
#define KDIM   4096
#define NE     16
#define NSLICE 16                  // K split across blocks -> 2048 blocks
#define TB     64                  // tokens per block (= wave width)
#define NWAVE  4                   // waves per block (256 threads)
#define KSLICE (KDIM / NSLICE)     // 256
#define KWAVE  (KSLICE / NWAVE)    // 64 k-columns per wave = 16 float4 cols

// async global->LDS DMA, 16B per lane; LDS dest = lptr + lane*16 (wave-uniform base)
__device__ __forceinline__ void async_ld16(const float* g, float* l) {
  __builtin_amdgcn_global_load_lds(
      (const __attribute__((address_space(1))) void*)g,
      (__attribute__((address_space(3))) void*)l, 16, 0, 0);
}

// Kernel A: partial logits via global_load_lds (no staging VGPRs -> no scratch
// spill, which round-2/3 counters convicted: WRITE_SIZE 128 MB @ VGPR=52).
// Per-wave private 64tok x 64k tile in LDS, 16 DMA instrs issued up front,
// AITER-style partial vmcnt waits (8 -> 0), no barrier in the hot path.
// Bank conflicts: DMA forces lane-linear LDS (no padding), so the global
// source is XOR-swizzled within each 128B token-row-half: slot q holds column
// q^(tau&7). Read of col c at slot c^(t&7) -> 8 lane-classes on 8 distinct
// 4-bank groups = 8 phases per ds_read_b128 = minimum (conflict-free).
__global__ __launch_bounds__(256)
void router_partial(const float* __restrict__ x, const float* __restrict__ gate,
                    float* __restrict__ ws) {
  __shared__ __align__(16) float lds[NWAVE * TB * KWAVE];  // 4 * 16 KB = 64 KB
  const int tid  = threadIdx.x;
  const int lane = tid & 63;
  const int w    = __builtin_amdgcn_readfirstlane(tid >> 6);
  const int g    = blockIdx.x >> 4;          // token group (128)
  const int s    = blockIdx.x & 15;          // k-slice (16)
  const int t0   = g * TB;
  const int k0   = s * KSLICE + w * KWAVE;
  float* xt = lds + w * (TB * KWAVE);

  // ---- issue all 16 DMAs (2 halves x 8 instrs); each instr = 8 tokens x 128B
  const int tau_lo = lane >> 3;              // token within 8-token group
  const int q      = lane & 7;               // float4 slot within 128B half-row
#pragma unroll
  for (int h = 0; h < 2; ++h) {
#pragma unroll
    for (int r = 0; r < 8; ++r) {
      int tau  = r * 8 + tau_lo;
      int col4 = h * 8 + (q ^ (tau & 7));    // XOR swizzle, same 128B segment
      const float* gp = x + (size_t)(t0 + tau) * KDIM + (k0 + col4 * 4);
      float* lp = xt + h * 2048 + r * 256;   // + lane*4 floats implicit
      async_ld16(gp, lp);
    }
  }

  float acc[NE];
#pragma unroll
  for (int e = 0; e < NE; ++e) acc[e] = 0.f;

  const int sw = lane & 7;
#pragma unroll
  for (int h = 0; h < 2; ++h) {
    // h=0: wait first 8 DMAs (8 still in flight); h=1: drain all
    if (h == 0) __builtin_amdgcn_s_waitcnt(0x0f78);  // vmcnt(8)
    else        __builtin_amdgcn_s_waitcnt(0x0f70);  // vmcnt(0)
    const float* xrow = xt + h * 2048 + lane * 32;   // my token's half-row
#pragma unroll
    for (int c = 0; c < 8; ++c) {            // 8 float4 cols per half
      int slot = c ^ sw;
      float4 xv4 = *(const float4*)(xrow + slot * 4);
      const float xv[4] = {xv4.x, xv4.y, xv4.z, xv4.w};
      int kk = k0 + h * 32 + c * 4;
#pragma unroll
      for (int m = 0; m < 4; ++m) {
        const float* grow = gate + (size_t)(kk + m) * NE;  // wave-uniform -> s_load
#pragma unroll
        for (int e = 0; e < NE; ++e) acc[e] = fmaf(xv[m], grow[e], acc[e]);
      }
    }
  }

  // ---- cross-wave reduction of the 4 k-subslices, one ws float4 per thread
  __syncthreads();                           // all waves done with their tiles
  float* red = lds;                          // reuse as [256][17]
#pragma unroll
  for (int e = 0; e < NE; ++e) red[(w * 64 + lane) * 17 + e] = acc[e];
  __syncthreads();
  {
    int p0 = tid * 4;                        // 1024 (token,e) pairs, 4/thread
    int t  = p0 >> 4, e0 = p0 & 15;
    float v[4];
#pragma unroll
    for (int j = 0; j < 4; ++j) {
      float sum = 0.f;
#pragma unroll
      for (int ww = 0; ww < NWAVE; ++ww) sum += red[(ww * 64 + t) * 17 + e0 + j];
      v[j] = sum;
    }
    *(float4*)(ws + ((size_t)s * N_TOK + (t0 + t)) * NE + e0) =
        make_float4(v[0], v[1], v[2], v[3]);
  }
}

// Kernel B: sum 16 slice partials, top-2 (earliest-index tie-break = jax
// top_k), sigmoid, scatter into (E,N) scores; token_indices[e][t] = t.
__global__ __launch_bounds__(256)
void router_finalize(const float* __restrict__ ws, float* __restrict__ out) {
  int t = blockIdx.x * 256 + threadIdx.x;
  float l[NE];
#pragma unroll
  for (int e = 0; e < NE; ++e) l[e] = 0.f;
#pragma unroll
  for (int s = 0; s < NSLICE; ++s) {
    const float* row = ws + ((size_t)s * N_TOK + t) * NE;  // 64B/thread
#pragma unroll
    for (int e = 0; e < NE; ++e) l[e] += row[e];
  }
  int i1 = 0; float v1 = l[0];
#pragma unroll
  for (int e = 1; e < NE; ++e) { if (l[e] > v1) { v1 = l[e]; i1 = e; } }
  int i2 = -1; float v2 = -1e30f;
#pragma unroll
  for (int e = 0; e < NE; ++e) { if (e != i1 && l[e] > v2) { v2 = l[e]; i2 = e; } }
  float s1 = 1.f / (1.f + __expf(-v1));
  float s2 = 1.f / (1.f + __expf(-v2));
  float* scores = out;
  float* tix    = out + (size_t)NE * N_TOK;
  float tf = (float)t;
#pragma unroll
  for (int e = 0; e < NE; ++e) {             // coalesced across lanes per e
    scores[(size_t)e * N_TOK + t] = (e == i1) ? s1 : ((e == i2) ? s2 : 0.f);
    tix[(size_t)e * N_TOK + t]    = tf;
  }
}

extern "C" void kernel_launch(void* const* d_in, const int* in_sizes, int n_in,
                              void* d_out, int out_size, void* d_ws, size_t ws_size,
                              hipStream_t stream) {
  const float* x    = (const float*)d_in[0];
  const float* gate = (const float*)d_in[1];
  float* out = (float*)d_out;
  float* ws  = (float*)d_ws;   // needs NSLICE*N_TOK*NE*4 = 8 MB
  router_partial<<<dim3(N_TOK / TB * NSLICE), dim3(256), 0, stream>>>(x, gate, ws);
  router_finalize<<<dim3(N_TOK / 256), dim3(256), 0, stream>>>(ws, out);
}